// Round 1
// baseline (724.178 us; speedup 1.0000x reference)
//
#include <hip/hip_runtime.h>

#define CH 64

// ---------- CSR build ----------
__global__ void hist_kernel(const int* __restrict__ dst, int* __restrict__ deg, int E) {
    int i = blockIdx.x * blockDim.x + threadIdx.x;
    if (i < E) atomicAdd(&deg[dst[i]], 1);
}

__global__ void scan_sums_kernel(const int* __restrict__ deg, int* __restrict__ bsums, int n) {
    __shared__ int s[256];
    int i = blockIdx.x * 256 + threadIdx.x;
    s[threadIdx.x] = (i < n) ? deg[i] : 0;
    __syncthreads();
    for (int off = 128; off > 0; off >>= 1) {
        if (threadIdx.x < off) s[threadIdx.x] += s[threadIdx.x + off];
        __syncthreads();
    }
    if (threadIdx.x == 0) bsums[blockIdx.x] = s[0];
}

__global__ void scan_bsums_kernel(int* bsums, int nb) {
    // single block, nb <= 256, exclusive scan in place
    __shared__ int s[256];
    int t = threadIdx.x;
    int orig = (t < nb) ? bsums[t] : 0;
    s[t] = orig;
    __syncthreads();
    for (int off = 1; off < 256; off <<= 1) {
        int add = (t >= off) ? s[t - off] : 0;
        __syncthreads();
        s[t] += add;
        __syncthreads();
    }
    if (t < nb) bsums[t] = s[t] - orig;  // exclusive
}

__global__ void scan_final_kernel(const int* __restrict__ deg, const int* __restrict__ bsums,
                                  int* __restrict__ rowptr, int* __restrict__ cursor,
                                  float* __restrict__ dinv, int n, int E) {
    __shared__ int s[256];
    int t = threadIdx.x;
    int i = blockIdx.x * 256 + t;
    int v = (i < n) ? deg[i] : 0;
    s[t] = v;
    __syncthreads();
    for (int off = 1; off < 256; off <<= 1) {
        int add = (t >= off) ? s[t - off] : 0;
        __syncthreads();
        s[t] += add;
        __syncthreads();
    }
    if (i < n) {
        int excl = bsums[blockIdx.x] + s[t] - v;  // exclusive prefix
        rowptr[i] = excl;
        cursor[i] = excl;
        dinv[i] = rsqrtf((float)(v + 1));  // deg = indeg + 1 (self loop), always > 0
    }
    if (i == 0) rowptr[n] = E;
}

__global__ void fill_kernel(const int* __restrict__ src, const int* __restrict__ dst,
                            int* __restrict__ cursor, int* __restrict__ csr, int E) {
    int i = blockIdx.x * blockDim.x + threadIdx.x;
    if (i < E) {
        int p = atomicAdd(&cursor[dst[i]], 1);
        csr[p] = src[i];
    }
}

// ---------- GEMM + dinv prescale: G = dinv ⊙ (X @ W) ----------
template <int K>
__global__ __launch_bounds__(256) void gemm_scale_kernel(
        const float* __restrict__ X, const float* __restrict__ W,
        const float* __restrict__ dinv, float* __restrict__ G, int N) {
    __shared__ float Ws[K * CH];
    for (int i = threadIdx.x; i < K * CH; i += 256) Ws[i] = W[i];
    __syncthreads();
    int lane = threadIdx.x & 63;
    int row = (blockIdx.x * 256 + threadIdx.x) >> 6;  // one wave per row
    if (row >= N) return;
    const float* xr = X + (size_t)row * K;
    float acc = 0.f;
#pragma unroll 16
    for (int k = 0; k < K; ++k) acc = fmaf(xr[k], Ws[k * CH + lane], acc);
    G[(size_t)row * CH + lane] = acc * dinv[row];
}

// ---------- gather aggregation: out[v] = dinv[v]*(g[v] + sum_{u -> v} g[u]) ----------
__global__ __launch_bounds__(256) void aggregate_kernel(
        const float* __restrict__ G, const int* __restrict__ rowptr,
        const int* __restrict__ csr, const float* __restrict__ dinv,
        float* __restrict__ Out, int N, int relu) {
    int lane = threadIdx.x & 63;
    int v = (blockIdx.x * 256 + threadIdx.x) >> 6;  // one wave per node
    if (v >= N) return;
    float acc = G[(size_t)v * CH + lane];  // self loop
    int beg = rowptr[v], end = rowptr[v + 1];
#pragma unroll 4
    for (int e = beg; e < end; ++e) {
        int u = __builtin_amdgcn_readfirstlane(csr[e]);  // wave-uniform -> SGPR base
        acc += G[(size_t)u * CH + lane];
    }
    float o = acc * dinv[v];
    if (relu) o = fmaxf(o, 0.f);
    Out[(size_t)v * CH + lane] = o;
}

// ---------- pooling ----------
__global__ __launch_bounds__(256) void pool_kernel(
        const float* __restrict__ H, const int* __restrict__ batch,
        float* __restrict__ sums, int* __restrict__ cnts, int N) {
    int lane = threadIdx.x & 63;
    int v = (blockIdx.x * 256 + threadIdx.x) >> 6;
    if (v >= N) return;
    int g = batch[v];
    atomicAdd(&sums[(size_t)g * CH + lane], H[(size_t)v * CH + lane]);
    if (lane == 0) atomicAdd(&cnts[g], 1);
}

__global__ void head_kernel(const float* __restrict__ sums, const int* __restrict__ cnts,
                            const float* __restrict__ Wl, const float* __restrict__ bl,
                            float* __restrict__ out, int NG) {
    int g = blockIdx.x;
    int lane = threadIdx.x;  // 64 threads = 1 wave
    float c = fmaxf((float)cnts[g], 1.0f);
    float p = sums[(size_t)g * CH + lane] / c;
    for (int o = 0; o < 10; ++o) {
        float t = p * Wl[lane * 10 + o];
        for (int off = 32; off > 0; off >>= 1) t += __shfl_down(t, off);
        if (lane == 0) out[g * 10 + o] = t + bl[o];
    }
}

extern "C" void kernel_launch(void* const* d_in, const int* in_sizes, int n_in,
                              void* d_out, int out_size, void* d_ws, size_t ws_size,
                              hipStream_t stream) {
    const float* x     = (const float*)d_in[0];
    const int*   ei    = (const int*)d_in[1];
    const int*   batch = (const int*)d_in[2];
    const float* W1    = (const float*)d_in[3];
    const float* W2    = (const float*)d_in[4];
    const float* W3    = (const float*)d_in[5];
    const float* Wl    = (const float*)d_in[6];
    const float* bl    = (const float*)d_in[7];
    float* out = (float*)d_out;

    const int N  = in_sizes[0] / 128;  // 50000
    const int E  = in_sizes[1] / 2;    // 1250000
    const int NG = out_size / 10;      // 500

    const int* src = ei;
    const int* dst = ei + E;

    // workspace carve-out (256B aligned), ~31.5 MB total
    char* ws = (char*)d_ws;
    size_t off = 0;
    auto alloc = [&](size_t bytes) -> void* {
        void* p = ws + off;
        off += bytes;
        off = (off + 255) & ~(size_t)255;
        return p;
    };
    int*   deg    = (int*)alloc((size_t)N * 4);
    int*   rowptr = (int*)alloc((size_t)(N + 1) * 4);
    int*   cursor = (int*)alloc((size_t)N * 4);
    int*   bsums  = (int*)alloc(256 * 4);
    int*   csr    = (int*)alloc((size_t)E * 4);
    float* dinv   = (float*)alloc((size_t)N * 4);
    float* bufA   = (float*)alloc((size_t)N * CH * 4);
    float* bufB   = (float*)alloc((size_t)N * CH * 4);
    float* pooled = (float*)alloc((size_t)NG * CH * 4);
    int*   cnts   = (int*)alloc((size_t)NG * 4);

    hipMemsetAsync(deg, 0, (size_t)N * 4, stream);
    hipMemsetAsync(pooled, 0, (size_t)NG * CH * 4, stream);
    hipMemsetAsync(cnts, 0, (size_t)NG * 4, stream);

    int eb = (E + 255) / 256;
    int nb = (N + 255) / 256;  // 196 <= 256 (scan_bsums assumption)
    int wb = (N + 3) / 4;      // 4 waves per 256-thread block, one wave per node/row

    hist_kernel<<<eb, 256, 0, stream>>>(dst, deg, E);
    scan_sums_kernel<<<nb, 256, 0, stream>>>(deg, bsums, N);
    scan_bsums_kernel<<<1, 256, 0, stream>>>(bsums, nb);
    scan_final_kernel<<<nb, 256, 0, stream>>>(deg, bsums, rowptr, cursor, dinv, N, E);
    fill_kernel<<<eb, 256, 0, stream>>>(src, dst, cursor, csr, E);

    // layer 1: 128 -> 64, relu
    gemm_scale_kernel<128><<<wb, 256, 0, stream>>>(x, W1, dinv, bufA, N);
    aggregate_kernel<<<wb, 256, 0, stream>>>(bufA, rowptr, csr, dinv, bufB, N, 1);
    // layer 2: 64 -> 64, relu
    gemm_scale_kernel<64><<<wb, 256, 0, stream>>>(bufB, W2, dinv, bufA, N);
    aggregate_kernel<<<wb, 256, 0, stream>>>(bufA, rowptr, csr, dinv, bufB, N, 1);
    // layer 3: 64 -> 64, no relu
    gemm_scale_kernel<64><<<wb, 256, 0, stream>>>(bufB, W3, dinv, bufA, N);
    aggregate_kernel<<<wb, 256, 0, stream>>>(bufA, rowptr, csr, dinv, bufB, N, 0);

    // mean pool + linear head
    pool_kernel<<<wb, 256, 0, stream>>>(bufB, batch, pooled, cnts, N);
    head_kernel<<<NG, 64, 0, stream>>>(pooled, cnts, Wl, bl, out, NG);
}

// Round 2
// 510.893 us; speedup vs baseline: 1.4175x; 1.4175x over previous
//
#include <hip/hip_runtime.h>

#define CH 64

// ---------- CSR build ----------
__global__ void hist_kernel(const int* __restrict__ dst, int* __restrict__ deg, int E) {
    int i = blockIdx.x * blockDim.x + threadIdx.x;
    if (i < E) atomicAdd(&deg[dst[i]], 1);
}

__global__ void scan_sums_kernel(const int* __restrict__ deg, int* __restrict__ bsums, int n) {
    __shared__ int s[256];
    int i = blockIdx.x * 256 + threadIdx.x;
    s[threadIdx.x] = (i < n) ? deg[i] : 0;
    __syncthreads();
    for (int off = 128; off > 0; off >>= 1) {
        if (threadIdx.x < off) s[threadIdx.x] += s[threadIdx.x + off];
        __syncthreads();
    }
    if (threadIdx.x == 0) bsums[blockIdx.x] = s[0];
}

__global__ void scan_bsums_kernel(int* bsums, int nb) {
    // single block, nb <= 256, exclusive scan in place
    __shared__ int s[256];
    int t = threadIdx.x;
    int orig = (t < nb) ? bsums[t] : 0;
    s[t] = orig;
    __syncthreads();
    for (int off = 1; off < 256; off <<= 1) {
        int add = (t >= off) ? s[t - off] : 0;
        __syncthreads();
        s[t] += add;
        __syncthreads();
    }
    if (t < nb) bsums[t] = s[t] - orig;  // exclusive
}

__global__ void scan_final_kernel(const int* __restrict__ deg, const int* __restrict__ bsums,
                                  int* __restrict__ rowptr, int* __restrict__ cursor,
                                  float* __restrict__ dinv, int n, int E) {
    __shared__ int s[256];
    int t = threadIdx.x;
    int i = blockIdx.x * 256 + t;
    int v = (i < n) ? deg[i] : 0;
    s[t] = v;
    __syncthreads();
    for (int off = 1; off < 256; off <<= 1) {
        int add = (t >= off) ? s[t - off] : 0;
        __syncthreads();
        s[t] += add;
        __syncthreads();
    }
    if (i < n) {
        int excl = bsums[blockIdx.x] + s[t] - v;  // exclusive prefix
        rowptr[i] = excl;
        cursor[i] = excl;
        dinv[i] = rsqrtf((float)(v + 1));  // deg = indeg + 1 (self loop), always > 0
    }
    if (i == 0) rowptr[n] = E;
}

__global__ void fill_kernel(const int* __restrict__ src, const int* __restrict__ dst,
                            int* __restrict__ cursor, int* __restrict__ csr, int E) {
    int i = blockIdx.x * blockDim.x + threadIdx.x;
    if (i < E) {
        int p = atomicAdd(&cursor[dst[i]], 1);
        csr[p] = src[i];
    }
}

// ---------- GEMM + dinv prescale: G = dinv ⊙ (X @ W) ----------
template <int K>
__global__ __launch_bounds__(256) void gemm_scale_kernel(
        const float* __restrict__ X, const float* __restrict__ W,
        const float* __restrict__ dinv, float* __restrict__ G, int N) {
    __shared__ float Ws[K * CH];
    for (int i = threadIdx.x; i < K * CH; i += 256) Ws[i] = W[i];
    __syncthreads();
    int lane = threadIdx.x & 63;
    int row = (blockIdx.x * 256 + threadIdx.x) >> 6;  // one wave per row
    if (row >= N) return;
    const float* xr = X + (size_t)row * K;
    float acc = 0.f;
#pragma unroll 16
    for (int k = 0; k < K; ++k) acc = fmaf(xr[k], Ws[k * CH + lane], acc);
    G[(size_t)row * CH + lane] = acc * dinv[row];
}

// ---------- gather aggregation: out[v] = dinv[v]*(g[v] + sum_{u -> v} g[u]) ----------
// One wave per node. Lane layout: 4 groups of 16 lanes; group g handles edge e+g,
// each lane reads float4 (16B) of row u -> one 1KB gather instruction covers 4 edges.
__global__ __launch_bounds__(256) void aggregate_kernel(
        const float* __restrict__ G, const int* __restrict__ rowptr,
        const int* __restrict__ csr, const float* __restrict__ dinv,
        float* __restrict__ Out, int N, int relu) {
    int lane = threadIdx.x & 63;
    int v = (blockIdx.x * 256 + threadIdx.x) >> 6;  // one wave per node
    if (v >= N) return;
    int grp = lane >> 4;   // 0..3 -> which edge in the 4-pack
    int cl  = lane & 15;   // float4 channel block (4 channels each)
    const float4* __restrict__ G4 = (const float4*)G;

    int beg = rowptr[v], end = rowptr[v + 1];
    float4 acc = {0.f, 0.f, 0.f, 0.f};
#pragma unroll 4
    for (int e = beg; e < end; e += 4) {
        int eg = e + grp;
        int raw = csr[eg];            // csr padded: always in-bounds
        bool ok = eg < end;
        int u = ok ? raw : 0;         // row 0 always exists
        float s = ok ? 1.f : 0.f;
        float4 g4 = G4[(size_t)u * 16 + cl];
        acc.x = fmaf(g4.x, s, acc.x);
        acc.y = fmaf(g4.y, s, acc.y);
        acc.z = fmaf(g4.z, s, acc.z);
        acc.w = fmaf(g4.w, s, acc.w);
    }
    // reduce across the 4 groups (channels identical across groups)
    acc.x += __shfl_xor(acc.x, 16); acc.y += __shfl_xor(acc.y, 16);
    acc.z += __shfl_xor(acc.z, 16); acc.w += __shfl_xor(acc.w, 16);
    acc.x += __shfl_xor(acc.x, 32); acc.y += __shfl_xor(acc.y, 32);
    acc.z += __shfl_xor(acc.z, 32); acc.w += __shfl_xor(acc.w, 32);

    if (lane < 16) {
        float4 self = G4[(size_t)v * 16 + lane];
        float d = dinv[v];
        float4 o;
        o.x = (acc.x + self.x) * d;
        o.y = (acc.y + self.y) * d;
        o.z = (acc.z + self.z) * d;
        o.w = (acc.w + self.w) * d;
        if (relu) {
            o.x = fmaxf(o.x, 0.f); o.y = fmaxf(o.y, 0.f);
            o.z = fmaxf(o.z, 0.f); o.w = fmaxf(o.w, 0.f);
        }
        ((float4*)Out)[(size_t)v * 16 + lane] = o;
    }
}

// ---------- pooling ----------
__global__ __launch_bounds__(256) void pool_kernel(
        const float* __restrict__ H, const int* __restrict__ batch,
        float* __restrict__ sums, int* __restrict__ cnts, int N) {
    int lane = threadIdx.x & 63;
    int v = (blockIdx.x * 256 + threadIdx.x) >> 6;
    if (v >= N) return;
    int g = batch[v];
    atomicAdd(&sums[(size_t)g * CH + lane], H[(size_t)v * CH + lane]);
    if (lane == 0) atomicAdd(&cnts[g], 1);
}

__global__ void head_kernel(const float* __restrict__ sums, const int* __restrict__ cnts,
                            const float* __restrict__ Wl, const float* __restrict__ bl,
                            float* __restrict__ out, int NG) {
    int g = blockIdx.x;
    int lane = threadIdx.x;  // 64 threads = 1 wave
    float c = fmaxf((float)cnts[g], 1.0f);
    float p = sums[(size_t)g * CH + lane] / c;
    for (int o = 0; o < 10; ++o) {
        float t = p * Wl[lane * 10 + o];
        for (int off = 32; off > 0; off >>= 1) t += __shfl_down(t, off);
        if (lane == 0) out[g * 10 + o] = t + bl[o];
    }
}

extern "C" void kernel_launch(void* const* d_in, const int* in_sizes, int n_in,
                              void* d_out, int out_size, void* d_ws, size_t ws_size,
                              hipStream_t stream) {
    const float* x     = (const float*)d_in[0];
    const int*   ei    = (const int*)d_in[1];
    const int*   batch = (const int*)d_in[2];
    const float* W1    = (const float*)d_in[3];
    const float* W2    = (const float*)d_in[4];
    const float* W3    = (const float*)d_in[5];
    const float* Wl    = (const float*)d_in[6];
    const float* bl    = (const float*)d_in[7];
    float* out = (float*)d_out;

    const int N  = in_sizes[0] / 128;  // 50000
    const int E  = in_sizes[1] / 2;    // 1250000
    const int NG = out_size / 10;      // 500

    const int* src = ei;
    const int* dst = ei + E;

    // workspace carve-out (256B aligned)
    char* ws = (char*)d_ws;
    size_t off = 0;
    auto alloc = [&](size_t bytes) -> void* {
        void* p = ws + off;
        off += bytes;
        off = (off + 255) & ~(size_t)255;
        return p;
    };
    int*   deg    = (int*)alloc((size_t)N * 4);
    int*   rowptr = (int*)alloc((size_t)(N + 1) * 4);
    int*   cursor = (int*)alloc((size_t)N * 4);
    int*   bsums  = (int*)alloc(256 * 4);
    int*   csr    = (int*)alloc((size_t)(E + 16) * 4);  // +16 pad: aggregate reads up to end+2
    float* dinv   = (float*)alloc((size_t)N * 4);
    float* bufA   = (float*)alloc((size_t)N * CH * 4);
    float* bufB   = (float*)alloc((size_t)N * CH * 4);
    float* pooled = (float*)alloc((size_t)NG * CH * 4);
    int*   cnts   = (int*)alloc((size_t)NG * 4);

    hipMemsetAsync(deg, 0, (size_t)N * 4, stream);
    hipMemsetAsync(pooled, 0, (size_t)NG * CH * 4, stream);
    hipMemsetAsync(cnts, 0, (size_t)NG * 4, stream);

    int eb = (E + 255) / 256;
    int nb = (N + 255) / 256;  // 196 <= 256 (scan_bsums assumption)
    int wb = (N + 3) / 4;      // 4 waves per 256-thread block, one wave per node/row

    hist_kernel<<<eb, 256, 0, stream>>>(dst, deg, E);
    scan_sums_kernel<<<nb, 256, 0, stream>>>(deg, bsums, N);
    scan_bsums_kernel<<<1, 256, 0, stream>>>(bsums, nb);
    scan_final_kernel<<<nb, 256, 0, stream>>>(deg, bsums, rowptr, cursor, dinv, N, E);
    fill_kernel<<<eb, 256, 0, stream>>>(src, dst, cursor, csr, E);

    // layer 1: 128 -> 64, relu
    gemm_scale_kernel<128><<<wb, 256, 0, stream>>>(x, W1, dinv, bufA, N);
    aggregate_kernel<<<wb, 256, 0, stream>>>(bufA, rowptr, csr, dinv, bufB, N, 1);
    // layer 2: 64 -> 64, relu
    gemm_scale_kernel<64><<<wb, 256, 0, stream>>>(bufB, W2, dinv, bufA, N);
    aggregate_kernel<<<wb, 256, 0, stream>>>(bufA, rowptr, csr, dinv, bufB, N, 1);
    // layer 3: 64 -> 64, no relu
    gemm_scale_kernel<64><<<wb, 256, 0, stream>>>(bufB, W3, dinv, bufA, N);
    aggregate_kernel<<<wb, 256, 0, stream>>>(bufA, rowptr, csr, dinv, bufB, N, 0);

    // mean pool + linear head
    pool_kernel<<<wb, 256, 0, stream>>>(bufB, batch, pooled, cnts, N);
    head_kernel<<<NG, 64, 0, stream>>>(pooled, cnts, Wl, bl, out, NG);
}

// Round 3
// 355.178 us; speedup vs baseline: 2.0389x; 1.4384x over previous
//
#include <hip/hip_runtime.h>

#define CH 64
#define CHUNK 4096
#define BSHIFT 8          // 256 nodes per bucket
#define NBUCK 196         // ceil(50000 / 256)

// ---------- pass 1: per-bucket histogram (dst >> 8) ----------
__global__ __launch_bounds__(256) void bucket_hist_kernel(
        const int* __restrict__ dst, int* __restrict__ bucket_cnt, int E) {
    __shared__ int hist[256];
    int tid = threadIdx.x;
    int e0 = blockIdx.x * CHUNK;
    int total = min(CHUNK, E - e0);
    hist[tid] = 0;
    __syncthreads();
    for (int i = tid; i < total; i += 256)
        atomicAdd(&hist[dst[e0 + i] >> BSHIFT], 1);
    __syncthreads();
    if (tid < NBUCK && hist[tid]) atomicAdd(&bucket_cnt[tid], hist[tid]);
}

// ---------- pass 2: scan bucket counts -> base & cursor ----------
__global__ __launch_bounds__(256) void bucket_scan_kernel(
        const int* __restrict__ cnt, int* __restrict__ base,
        int* __restrict__ cursor, int* __restrict__ rowptr, int N, int E) {
    __shared__ int sc[256];
    int tid = threadIdx.x;
    int c = (tid < NBUCK) ? cnt[tid] : 0;
    sc[tid] = c;
    __syncthreads();
    for (int off = 1; off < 256; off <<= 1) {
        int v = (tid >= off) ? sc[tid - off] : 0;
        __syncthreads();
        sc[tid] += v;
        __syncthreads();
    }
    if (tid < NBUCK) { base[tid] = sc[tid] - c; cursor[tid] = sc[tid] - c; }
    if (tid == NBUCK - 1) base[NBUCK] = sc[tid];
    if (tid == 0) rowptr[N] = E;
}

// ---------- pass 3: bin edges into bucket regions (coalesced flush) ----------
__global__ __launch_bounds__(256) void bin_kernel(
        const int* __restrict__ src, const int* __restrict__ dst,
        int* __restrict__ cursor, int2* __restrict__ pairs, int E) {
    __shared__ int2 stage[CHUNK];                         // 32 KB
    __shared__ int hist[256], sc[256], lbase[256], lcur[256], gbase[256];
    int tid = threadIdx.x;
    int e0 = blockIdx.x * CHUNK;
    int total = min(CHUNK, E - e0);
    hist[tid] = 0;
    __syncthreads();
    for (int i = tid; i < total; i += 256)
        atomicAdd(&hist[dst[e0 + i] >> BSHIFT], 1);
    __syncthreads();
    sc[tid] = hist[tid];
    __syncthreads();
    for (int off = 1; off < 256; off <<= 1) {
        int v = (tid >= off) ? sc[tid - off] : 0;
        __syncthreads();
        sc[tid] += v;
        __syncthreads();
    }
    lbase[tid] = sc[tid] - hist[tid];
    lcur[tid]  = sc[tid] - hist[tid];
    if (tid < NBUCK && hist[tid] > 0) gbase[tid] = atomicAdd(&cursor[tid], hist[tid]);
    __syncthreads();
    for (int i = tid; i < total; i += 256) {
        int s = src[e0 + i], d = dst[e0 + i];
        int pos = atomicAdd(&lcur[d >> BSHIFT], 1);
        stage[pos] = make_int2(s, d);
    }
    __syncthreads();
    for (int i = tid; i < total; i += 256) {
        int2 p = stage[i];
        int b = p.y >> BSHIFT;
        pairs[gbase[b] + (i - lbase[b])] = p;            // coalesced per segment
    }
}

// ---------- pass 4: per-bucket counting sort -> csr, rowptr, dinv ----------
__global__ __launch_bounds__(256) void bucket_sort_kernel(
        const int2* __restrict__ pairs, const int* __restrict__ base,
        int* __restrict__ csr, int* __restrict__ rowptr,
        float* __restrict__ dinv, int N) {
    __shared__ int cntl[256], sc[256], cur[256];
    int tid = threadIdx.x;
    int b = blockIdx.x;
    int lo = b << BSHIFT;
    int pbase = base[b], pend = base[b + 1];
    int cnt = pend - pbase;
    cntl[tid] = 0;
    __syncthreads();
    for (int i = tid; i < cnt; i += 256)
        atomicAdd(&cntl[pairs[pbase + i].y - lo], 1);
    __syncthreads();
    sc[tid] = cntl[tid];
    __syncthreads();
    for (int off = 1; off < 256; off <<= 1) {
        int v = (tid >= off) ? sc[tid - off] : 0;
        __syncthreads();
        sc[tid] += v;
        __syncthreads();
    }
    int excl = sc[tid] - cntl[tid];
    cur[tid] = excl;
    int v = lo + tid;
    if (v < N) {
        rowptr[v] = pbase + excl;
        dinv[v] = rsqrtf((float)(cntl[tid] + 1));  // deg = indeg + 1 (self loop)
    }
    __syncthreads();
    for (int i = tid; i < cnt; i += 256) {
        int2 p = pairs[pbase + i];
        int pos = atomicAdd(&cur[p.y - lo], 1);
        csr[pbase + pos] = p.x;                          // 25 KB region, single block
    }
}

// ---------- GEMM + dinv prescale: G = dinv ⊙ (X @ W) ----------
template <int K>
__global__ __launch_bounds__(256) void gemm_scale_kernel(
        const float* __restrict__ X, const float* __restrict__ W,
        const float* __restrict__ dinv, float* __restrict__ G, int N) {
    __shared__ float Ws[K * CH];
    for (int i = threadIdx.x; i < K * CH; i += 256) Ws[i] = W[i];
    __syncthreads();
    int lane = threadIdx.x & 63;
    int row = (blockIdx.x * 256 + threadIdx.x) >> 6;  // one wave per row
    if (row >= N) return;
    const float* xr = X + (size_t)row * K;
    float acc = 0.f;
#pragma unroll 16
    for (int k = 0; k < K; ++k) acc = fmaf(xr[k], Ws[k * CH + lane], acc);
    G[(size_t)row * CH + lane] = acc * dinv[row];
}

// ---------- gather aggregation: out[v] = dinv[v]*(g[v] + sum_{u -> v} g[u]) ----------
__global__ __launch_bounds__(256) void aggregate_kernel(
        const float* __restrict__ G, const int* __restrict__ rowptr,
        const int* __restrict__ csr, const float* __restrict__ dinv,
        float* __restrict__ Out, int N, int relu) {
    int lane = threadIdx.x & 63;
    int v = (blockIdx.x * 256 + threadIdx.x) >> 6;  // one wave per node
    if (v >= N) return;
    int grp = lane >> 4;   // 0..3 -> which edge in the 4-pack
    int cl  = lane & 15;   // float4 channel block
    const float4* __restrict__ G4 = (const float4*)G;

    int beg = rowptr[v], end = rowptr[v + 1];
    float4 acc = {0.f, 0.f, 0.f, 0.f};
#pragma unroll 4
    for (int e = beg; e < end; e += 4) {
        int eg = e + grp;
        int raw = csr[eg];            // csr padded: always in-bounds
        bool ok = eg < end;
        int u = ok ? raw : 0;
        float s = ok ? 1.f : 0.f;
        float4 g4 = G4[(size_t)u * 16 + cl];
        acc.x = fmaf(g4.x, s, acc.x);
        acc.y = fmaf(g4.y, s, acc.y);
        acc.z = fmaf(g4.z, s, acc.z);
        acc.w = fmaf(g4.w, s, acc.w);
    }
    acc.x += __shfl_xor(acc.x, 16); acc.y += __shfl_xor(acc.y, 16);
    acc.z += __shfl_xor(acc.z, 16); acc.w += __shfl_xor(acc.w, 16);
    acc.x += __shfl_xor(acc.x, 32); acc.y += __shfl_xor(acc.y, 32);
    acc.z += __shfl_xor(acc.z, 32); acc.w += __shfl_xor(acc.w, 32);

    if (lane < 16) {
        float4 self = G4[(size_t)v * 16 + lane];
        float d = dinv[v];
        float4 o;
        o.x = (acc.x + self.x) * d;
        o.y = (acc.y + self.y) * d;
        o.z = (acc.z + self.z) * d;
        o.w = (acc.w + self.w) * d;
        if (relu) {
            o.x = fmaxf(o.x, 0.f); o.y = fmaxf(o.y, 0.f);
            o.z = fmaxf(o.z, 0.f); o.w = fmaxf(o.w, 0.f);
        }
        ((float4*)Out)[(size_t)v * 16 + lane] = o;
    }
}

// ---------- graph boundaries via binary search (batch is sorted) ----------
__global__ void gptr_kernel(const int* __restrict__ batch, int* __restrict__ gptr,
                            int N, int NG) {
    int g = blockIdx.x * blockDim.x + threadIdx.x;
    if (g > NG) return;
    if (g == NG) { gptr[NG] = N; return; }
    int lo = 0, hi = N;
    while (lo < hi) {
        int mid = (lo + hi) >> 1;
        if (batch[mid] < g) lo = mid + 1; else hi = mid;
    }
    gptr[g] = lo;  // first index with batch[i] >= g
}

// ---------- fused mean-pool + linear head ----------
__global__ __launch_bounds__(64) void pool_head_kernel(
        const float* __restrict__ H, const int* __restrict__ gptr,
        const float* __restrict__ Wl, const float* __restrict__ bl,
        float* __restrict__ out, int NG) {
    int g = blockIdx.x;
    int lane = threadIdx.x;  // 64 = CH
    int s = gptr[g], e = gptr[g + 1];
    float acc = 0.f;
    for (int v = s; v < e; ++v) acc += H[(size_t)v * CH + lane];
    float c = (float)(e - s);
    float mean = (c > 0.f) ? acc / c : 0.f;
    for (int o = 0; o < 10; ++o) {
        float t = mean * Wl[lane * 10 + o];
        for (int off = 32; off > 0; off >>= 1) t += __shfl_down(t, off);
        if (lane == 0) out[g * 10 + o] = t + bl[o];
    }
}

extern "C" void kernel_launch(void* const* d_in, const int* in_sizes, int n_in,
                              void* d_out, int out_size, void* d_ws, size_t ws_size,
                              hipStream_t stream) {
    const float* x     = (const float*)d_in[0];
    const int*   ei    = (const int*)d_in[1];
    const int*   batch = (const int*)d_in[2];
    const float* W1    = (const float*)d_in[3];
    const float* W2    = (const float*)d_in[4];
    const float* W3    = (const float*)d_in[5];
    const float* Wl    = (const float*)d_in[6];
    const float* bl    = (const float*)d_in[7];
    float* out = (float*)d_out;

    const int N  = in_sizes[0] / 128;  // 50000
    const int E  = in_sizes[1] / 2;    // 1250000
    const int NG = out_size / 10;      // 500

    const int* src = ei;
    const int* dst = ei + E;

    // workspace carve-out (256B aligned)
    char* ws = (char*)d_ws;
    size_t off = 0;
    auto alloc = [&](size_t bytes) -> void* {
        void* p = ws + off;
        off += bytes;
        off = (off + 255) & ~(size_t)255;
        return p;
    };
    int*   bucket_cnt    = (int*)alloc((size_t)NBUCK * 4);
    int*   bucket_base   = (int*)alloc((size_t)(NBUCK + 1) * 4);
    int*   bucket_cursor = (int*)alloc((size_t)NBUCK * 4);
    int*   csr    = (int*)alloc((size_t)(E + 16) * 4);   // +pad: aggregate reads end+3
    int*   rowptr = (int*)alloc((size_t)(N + 1) * 4);
    float* dinv   = (float*)alloc((size_t)N * 4);
    int*   gptr   = (int*)alloc((size_t)(NG + 1) * 4);
    float* bufA   = (float*)alloc((size_t)N * CH * 4);   // also aliases pairs (10MB < 12.8MB)
    float* bufB   = (float*)alloc((size_t)N * CH * 4);
    int2*  pairs  = (int2*)bufA;  // CSR build finishes before gemm1 writes bufA

    hipMemsetAsync(bucket_cnt, 0, (size_t)NBUCK * 4, stream);

    int cb = (E + CHUNK - 1) / CHUNK;  // 306
    int wb = (N + 3) / 4;              // aggregate/gemm: 4 waves per block, 1 wave per node

    bucket_hist_kernel<<<cb, 256, 0, stream>>>(dst, bucket_cnt, E);
    bucket_scan_kernel<<<1, 256, 0, stream>>>(bucket_cnt, bucket_base, bucket_cursor,
                                              rowptr, N, E);
    bin_kernel<<<cb, 256, 0, stream>>>(src, dst, bucket_cursor, pairs, E);
    bucket_sort_kernel<<<NBUCK, 256, 0, stream>>>(pairs, bucket_base, csr, rowptr, dinv, N);
    gptr_kernel<<<(NG + 512) / 512, 512, 0, stream>>>(batch, gptr, N, NG);

    // layer 1: 128 -> 64, relu   (gemm1 overwrites bufA/pairs -- CSR already built)
    gemm_scale_kernel<128><<<wb, 256, 0, stream>>>(x, W1, dinv, bufA, N);
    aggregate_kernel<<<wb, 256, 0, stream>>>(bufA, rowptr, csr, dinv, bufB, N, 1);
    // layer 2: 64 -> 64, relu
    gemm_scale_kernel<64><<<wb, 256, 0, stream>>>(bufB, W2, dinv, bufA, N);
    aggregate_kernel<<<wb, 256, 0, stream>>>(bufA, rowptr, csr, dinv, bufB, N, 1);
    // layer 3: 64 -> 64, no relu
    gemm_scale_kernel<64><<<wb, 256, 0, stream>>>(bufB, W3, dinv, bufA, N);
    aggregate_kernel<<<wb, 256, 0, stream>>>(bufA, rowptr, csr, dinv, bufB, N, 0);

    // mean pool + linear head
    pool_head_kernel<<<NG, 64, 0, stream>>>(bufB, gptr, Wl, bl, out, NG);
}

// Round 4
// 303.002 us; speedup vs baseline: 2.3900x; 1.1722x over previous
//
#include <hip/hip_runtime.h>

#define CH 64
#define CHUNK 4096
#define BSHIFT 8          // 256 nodes per bucket
#define NBUCK 196         // ceil(50000 / 256)

// ---------- pass 1: per-bucket histogram (dst >> 8) ----------
__global__ __launch_bounds__(256) void bucket_hist_kernel(
        const int* __restrict__ dst, int* __restrict__ bucket_cnt, int E) {
    __shared__ int hist[256];
    int tid = threadIdx.x;
    int e0 = blockIdx.x * CHUNK;
    int total = min(CHUNK, E - e0);
    hist[tid] = 0;
    __syncthreads();
    for (int i = tid; i < total; i += 256)
        atomicAdd(&hist[dst[e0 + i] >> BSHIFT], 1);
    __syncthreads();
    if (tid < NBUCK && hist[tid]) atomicAdd(&bucket_cnt[tid], hist[tid]);
}

// ---------- pass 2: scan bucket counts -> base & cursor ----------
__global__ __launch_bounds__(256) void bucket_scan_kernel(
        const int* __restrict__ cnt, int* __restrict__ base,
        int* __restrict__ cursor, int* __restrict__ rowptr, int N, int E) {
    __shared__ int sc[256];
    int tid = threadIdx.x;
    int c = (tid < NBUCK) ? cnt[tid] : 0;
    sc[tid] = c;
    __syncthreads();
    for (int off = 1; off < 256; off <<= 1) {
        int v = (tid >= off) ? sc[tid - off] : 0;
        __syncthreads();
        sc[tid] += v;
        __syncthreads();
    }
    if (tid < NBUCK) { base[tid] = sc[tid] - c; cursor[tid] = sc[tid] - c; }
    if (tid == NBUCK - 1) base[NBUCK] = sc[tid];
    if (tid == 0) rowptr[N] = E;
}

// ---------- pass 3: bin edges into bucket regions (coalesced flush) ----------
__global__ __launch_bounds__(256) void bin_kernel(
        const int* __restrict__ src, const int* __restrict__ dst,
        int* __restrict__ cursor, int2* __restrict__ pairs, int E) {
    __shared__ int2 stage[CHUNK];                         // 32 KB
    __shared__ int hist[256], sc[256], lbase[256], lcur[256], gbase[256];
    int tid = threadIdx.x;
    int e0 = blockIdx.x * CHUNK;
    int total = min(CHUNK, E - e0);
    hist[tid] = 0;
    __syncthreads();
    for (int i = tid; i < total; i += 256)
        atomicAdd(&hist[dst[e0 + i] >> BSHIFT], 1);
    __syncthreads();
    sc[tid] = hist[tid];
    __syncthreads();
    for (int off = 1; off < 256; off <<= 1) {
        int v = (tid >= off) ? sc[tid - off] : 0;
        __syncthreads();
        sc[tid] += v;
        __syncthreads();
    }
    lbase[tid] = sc[tid] - hist[tid];
    lcur[tid]  = sc[tid] - hist[tid];
    if (tid < NBUCK && hist[tid] > 0) gbase[tid] = atomicAdd(&cursor[tid], hist[tid]);
    __syncthreads();
    for (int i = tid; i < total; i += 256) {
        int s = src[e0 + i], d = dst[e0 + i];
        int pos = atomicAdd(&lcur[d >> BSHIFT], 1);
        stage[pos] = make_int2(s, d);
    }
    __syncthreads();
    for (int i = tid; i < total; i += 256) {
        int2 p = stage[i];
        int b = p.y >> BSHIFT;
        pairs[gbase[b] + (i - lbase[b])] = p;            // coalesced per segment
    }
}

// ---------- pass 4: per-bucket counting sort -> csr, rowptr, dinv ----------
__global__ __launch_bounds__(256) void bucket_sort_kernel(
        const int2* __restrict__ pairs, const int* __restrict__ base,
        int* __restrict__ csr, int* __restrict__ rowptr,
        float* __restrict__ dinv, int N) {
    __shared__ int cntl[256], sc[256], cur[256];
    int tid = threadIdx.x;
    int b = blockIdx.x;
    int lo = b << BSHIFT;
    int pbase = base[b], pend = base[b + 1];
    int cnt = pend - pbase;
    cntl[tid] = 0;
    __syncthreads();
    for (int i = tid; i < cnt; i += 256)
        atomicAdd(&cntl[pairs[pbase + i].y - lo], 1);
    __syncthreads();
    sc[tid] = cntl[tid];
    __syncthreads();
    for (int off = 1; off < 256; off <<= 1) {
        int v = (tid >= off) ? sc[tid - off] : 0;
        __syncthreads();
        sc[tid] += v;
        __syncthreads();
    }
    int excl = sc[tid] - cntl[tid];
    cur[tid] = excl;
    int v = lo + tid;
    if (v < N) {
        rowptr[v] = pbase + excl;
        dinv[v] = rsqrtf((float)(cntl[tid] + 1));  // deg = indeg + 1 (self loop)
    }
    __syncthreads();
    for (int i = tid; i < cnt; i += 256) {
        int2 p = pairs[pbase + i];
        int pos = atomicAdd(&cur[p.y - lo], 1);
        csr[pbase + pos] = p.x;                          // 25 KB region, single block
    }
}

// ---------- GEMM + dinv prescale: G = dinv ⊙ (X @ W) ----------
// 8 rows per wave, lane = output column. One ds_read_b32 of W[k][lane] feeds
// 8 FMAs whose x operands are wave-uniform scalar (s_load) reads.
template <int K>
__global__ __launch_bounds__(256) void gemm_scale_kernel(
        const float* __restrict__ X, const float* __restrict__ W,
        const float* __restrict__ dinv, float* __restrict__ G, int N) {
    __shared__ float Ws[K * CH];
    for (int i = threadIdx.x; i < K * CH; i += 256) Ws[i] = W[i];
    __syncthreads();
    int lane = threadIdx.x & 63;
    int wid = threadIdx.x >> 6;  // 0..3
    int row0 = __builtin_amdgcn_readfirstlane((blockIdx.x * 4 + wid) * 8);
    if (row0 >= N) return;       // N % 8 == 0 -> full 8-row groups only
    const float* __restrict__ xp = X + (size_t)row0 * K;
    float acc[8] = {0.f, 0.f, 0.f, 0.f, 0.f, 0.f, 0.f, 0.f};
#pragma unroll 4
    for (int k = 0; k < K; ++k) {
        float w = Ws[k * CH + lane];
#pragma unroll
        for (int r = 0; r < 8; ++r)
            acc[r] = fmaf(xp[(size_t)r * K + k], w, acc[r]);
    }
#pragma unroll
    for (int r = 0; r < 8; ++r)
        G[(size_t)(row0 + r) * CH + lane] = acc[r] * dinv[row0 + r];
}

// ---------- gather aggregation: out[v] = dinv[v]*(g[v] + sum_{u -> v} g[u]) ----------
__global__ __launch_bounds__(256) void aggregate_kernel(
        const float* __restrict__ G, const int* __restrict__ rowptr,
        const int* __restrict__ csr, const float* __restrict__ dinv,
        float* __restrict__ Out, int N, int relu) {
    int lane = threadIdx.x & 63;
    int v = (blockIdx.x * 256 + threadIdx.x) >> 6;  // one wave per node
    if (v >= N) return;
    int grp = lane >> 4;   // 0..3 -> which edge in the 4-pack
    int cl  = lane & 15;   // float4 channel block
    const float4* __restrict__ G4 = (const float4*)G;

    int beg = rowptr[v], end = rowptr[v + 1];
    float4 acc = {0.f, 0.f, 0.f, 0.f};
#pragma unroll 4
    for (int e = beg; e < end; e += 4) {
        int eg = e + grp;
        int raw = csr[eg];            // csr padded: always in-bounds
        bool ok = eg < end;
        int u = ok ? raw : 0;
        float s = ok ? 1.f : 0.f;
        float4 g4 = G4[(size_t)u * 16 + cl];
        acc.x = fmaf(g4.x, s, acc.x);
        acc.y = fmaf(g4.y, s, acc.y);
        acc.z = fmaf(g4.z, s, acc.z);
        acc.w = fmaf(g4.w, s, acc.w);
    }
    acc.x += __shfl_xor(acc.x, 16); acc.y += __shfl_xor(acc.y, 16);
    acc.z += __shfl_xor(acc.z, 16); acc.w += __shfl_xor(acc.w, 16);
    acc.x += __shfl_xor(acc.x, 32); acc.y += __shfl_xor(acc.y, 32);
    acc.z += __shfl_xor(acc.z, 32); acc.w += __shfl_xor(acc.w, 32);

    if (lane < 16) {
        float4 self = G4[(size_t)v * 16 + lane];
        float d = dinv[v];
        float4 o;
        o.x = (acc.x + self.x) * d;
        o.y = (acc.y + self.y) * d;
        o.z = (acc.z + self.z) * d;
        o.w = (acc.w + self.w) * d;
        if (relu) {
            o.x = fmaxf(o.x, 0.f); o.y = fmaxf(o.y, 0.f);
            o.z = fmaxf(o.z, 0.f); o.w = fmaxf(o.w, 0.f);
        }
        ((float4*)Out)[(size_t)v * 16 + lane] = o;
    }
}

// ---------- graph boundaries via binary search (batch is sorted) ----------
__global__ void gptr_kernel(const int* __restrict__ batch, int* __restrict__ gptr,
                            int N, int NG) {
    int g = blockIdx.x * blockDim.x + threadIdx.x;
    if (g > NG) return;
    if (g == NG) { gptr[NG] = N; return; }
    int lo = 0, hi = N;
    while (lo < hi) {
        int mid = (lo + hi) >> 1;
        if (batch[mid] < g) lo = mid + 1; else hi = mid;
    }
    gptr[g] = lo;  // first index with batch[i] >= g
}

// ---------- fused mean-pool + linear head ----------
__global__ __launch_bounds__(64) void pool_head_kernel(
        const float* __restrict__ H, const int* __restrict__ gptr,
        const float* __restrict__ Wl, const float* __restrict__ bl,
        float* __restrict__ out, int NG) {
    int g = blockIdx.x;
    int lane = threadIdx.x;  // 64 = CH
    int s = gptr[g], e = gptr[g + 1];
    float acc = 0.f;
    for (int v = s; v < e; ++v) acc += H[(size_t)v * CH + lane];
    float c = (float)(e - s);
    float mean = (c > 0.f) ? acc / c : 0.f;
    for (int o = 0; o < 10; ++o) {
        float t = mean * Wl[lane * 10 + o];
        for (int off = 32; off > 0; off >>= 1) t += __shfl_down(t, off);
        if (lane == 0) out[g * 10 + o] = t + bl[o];
    }
}

extern "C" void kernel_launch(void* const* d_in, const int* in_sizes, int n_in,
                              void* d_out, int out_size, void* d_ws, size_t ws_size,
                              hipStream_t stream) {
    const float* x     = (const float*)d_in[0];
    const int*   ei    = (const int*)d_in[1];
    const int*   batch = (const int*)d_in[2];
    const float* W1    = (const float*)d_in[3];
    const float* W2    = (const float*)d_in[4];
    const float* W3    = (const float*)d_in[5];
    const float* Wl    = (const float*)d_in[6];
    const float* bl    = (const float*)d_in[7];
    float* out = (float*)d_out;

    const int N  = in_sizes[0] / 128;  // 50000
    const int E  = in_sizes[1] / 2;    // 1250000
    const int NG = out_size / 10;      // 500

    const int* src = ei;
    const int* dst = ei + E;

    // workspace carve-out (256B aligned)
    char* ws = (char*)d_ws;
    size_t off = 0;
    auto alloc = [&](size_t bytes) -> void* {
        void* p = ws + off;
        off += bytes;
        off = (off + 255) & ~(size_t)255;
        return p;
    };
    int*   bucket_cnt    = (int*)alloc((size_t)NBUCK * 4);
    int*   bucket_base   = (int*)alloc((size_t)(NBUCK + 1) * 4);
    int*   bucket_cursor = (int*)alloc((size_t)NBUCK * 4);
    int*   csr    = (int*)alloc((size_t)(E + 16) * 4);   // +pad: aggregate reads end+3
    int*   rowptr = (int*)alloc((size_t)(N + 1) * 4);
    float* dinv   = (float*)alloc((size_t)N * 4);
    int*   gptr   = (int*)alloc((size_t)(NG + 1) * 4);
    float* bufA   = (float*)alloc((size_t)N * CH * 4);   // also aliases pairs (10MB < 12.8MB)
    float* bufB   = (float*)alloc((size_t)N * CH * 4);
    int2*  pairs  = (int2*)bufA;  // CSR build finishes before gemm1 writes bufA

    hipMemsetAsync(bucket_cnt, 0, (size_t)NBUCK * 4, stream);

    int cb = (E + CHUNK - 1) / CHUNK;  // 306
    int wb = (N + 3) / 4;              // aggregate: 4 waves per block, 1 wave per node
    int gb = (N + 31) / 32;            // gemm: 4 waves per block, 8 rows per wave

    bucket_hist_kernel<<<cb, 256, 0, stream>>>(dst, bucket_cnt, E);
    bucket_scan_kernel<<<1, 256, 0, stream>>>(bucket_cnt, bucket_base, bucket_cursor,
                                              rowptr, N, E);
    bin_kernel<<<cb, 256, 0, stream>>>(src, dst, bucket_cursor, pairs, E);
    bucket_sort_kernel<<<NBUCK, 256, 0, stream>>>(pairs, bucket_base, csr, rowptr, dinv, N);
    gptr_kernel<<<(NG + 512) / 512, 512, 0, stream>>>(batch, gptr, N, NG);

    // layer 1: 128 -> 64, relu   (gemm1 overwrites bufA/pairs -- CSR already built)
    gemm_scale_kernel<128><<<gb, 256, 0, stream>>>(x, W1, dinv, bufA, N);
    aggregate_kernel<<<wb, 256, 0, stream>>>(bufA, rowptr, csr, dinv, bufB, N, 1);
    // layer 2: 64 -> 64, relu
    gemm_scale_kernel<64><<<gb, 256, 0, stream>>>(bufB, W2, dinv, bufA, N);
    aggregate_kernel<<<wb, 256, 0, stream>>>(bufA, rowptr, csr, dinv, bufB, N, 1);
    // layer 3: 64 -> 64, no relu
    gemm_scale_kernel<64><<<gb, 256, 0, stream>>>(bufB, W3, dinv, bufA, N);
    aggregate_kernel<<<wb, 256, 0, stream>>>(bufA, rowptr, csr, dinv, bufB, N, 0);

    // mean pool + linear head
    pool_head_kernel<<<NG, 64, 0, stream>>>(bufB, gptr, Wl, bl, out, NG);
}

// Round 5
// 286.165 us; speedup vs baseline: 2.5306x; 1.0588x over previous
//
#include <hip/hip_runtime.h>

#define CH 64
#define CHUNK 4096
#define BSHIFT 8          // 256 nodes per bucket
#define NBUCK 196         // ceil(50000 / 256)

// ---------- pass 1: per-bucket histogram (dst >> 8) ----------
__global__ __launch_bounds__(256) void bucket_hist_kernel(
        const int* __restrict__ dst, int* __restrict__ bucket_cnt, int E) {
    __shared__ int hist[256];
    int tid = threadIdx.x;
    int e0 = blockIdx.x * CHUNK;
    int total = min(CHUNK, E - e0);
    hist[tid] = 0;
    __syncthreads();
    for (int i = tid; i < total; i += 256)
        atomicAdd(&hist[dst[e0 + i] >> BSHIFT], 1);
    __syncthreads();
    if (tid < NBUCK && hist[tid]) atomicAdd(&bucket_cnt[tid], hist[tid]);
}

// ---------- pass 2: scan bucket counts -> base & cursor ----------
__global__ __launch_bounds__(256) void bucket_scan_kernel(
        const int* __restrict__ cnt, int* __restrict__ base,
        int* __restrict__ cursor, int* __restrict__ rowptr, int N, int E) {
    __shared__ int sc[256];
    int tid = threadIdx.x;
    int c = (tid < NBUCK) ? cnt[tid] : 0;
    sc[tid] = c;
    __syncthreads();
    for (int off = 1; off < 256; off <<= 1) {
        int v = (tid >= off) ? sc[tid - off] : 0;
        __syncthreads();
        sc[tid] += v;
        __syncthreads();
    }
    if (tid < NBUCK) { base[tid] = sc[tid] - c; cursor[tid] = sc[tid] - c; }
    if (tid == NBUCK - 1) base[NBUCK] = sc[tid];
    if (tid == 0) rowptr[N] = E;
}

// ---------- pass 3: bin edges into bucket regions (coalesced flush) ----------
__global__ __launch_bounds__(256) void bin_kernel(
        const int* __restrict__ src, const int* __restrict__ dst,
        int* __restrict__ cursor, int2* __restrict__ pairs, int E) {
    __shared__ int2 stage[CHUNK];                         // 32 KB
    __shared__ int hist[256], sc[256], lbase[256], lcur[256], gbase[256];
    int tid = threadIdx.x;
    int e0 = blockIdx.x * CHUNK;
    int total = min(CHUNK, E - e0);
    hist[tid] = 0;
    __syncthreads();
    for (int i = tid; i < total; i += 256)
        atomicAdd(&hist[dst[e0 + i] >> BSHIFT], 1);
    __syncthreads();
    sc[tid] = hist[tid];
    __syncthreads();
    for (int off = 1; off < 256; off <<= 1) {
        int v = (tid >= off) ? sc[tid - off] : 0;
        __syncthreads();
        sc[tid] += v;
        __syncthreads();
    }
    lbase[tid] = sc[tid] - hist[tid];
    lcur[tid]  = sc[tid] - hist[tid];
    if (tid < NBUCK && hist[tid] > 0) gbase[tid] = atomicAdd(&cursor[tid], hist[tid]);
    __syncthreads();
    for (int i = tid; i < total; i += 256) {
        int s = src[e0 + i], d = dst[e0 + i];
        int pos = atomicAdd(&lcur[d >> BSHIFT], 1);
        stage[pos] = make_int2(s, d);
    }
    __syncthreads();
    for (int i = tid; i < total; i += 256) {
        int2 p = stage[i];
        int b = p.y >> BSHIFT;
        pairs[gbase[b] + (i - lbase[b])] = p;            // coalesced per segment
    }
}

// ---------- pass 4: per-bucket counting sort -> csr, rowptr, dinv ----------
__global__ __launch_bounds__(256) void bucket_sort_kernel(
        const int2* __restrict__ pairs, const int* __restrict__ base,
        int* __restrict__ csr, int* __restrict__ rowptr,
        float* __restrict__ dinv, int N) {
    __shared__ int cntl[256], sc[256], cur[256];
    int tid = threadIdx.x;
    int b = blockIdx.x;
    int lo = b << BSHIFT;
    int pbase = base[b], pend = base[b + 1];
    int cnt = pend - pbase;
    cntl[tid] = 0;
    __syncthreads();
    for (int i = tid; i < cnt; i += 256)
        atomicAdd(&cntl[pairs[pbase + i].y - lo], 1);
    __syncthreads();
    sc[tid] = cntl[tid];
    __syncthreads();
    for (int off = 1; off < 256; off <<= 1) {
        int v = (tid >= off) ? sc[tid - off] : 0;
        __syncthreads();
        sc[tid] += v;
        __syncthreads();
    }
    int excl = sc[tid] - cntl[tid];
    cur[tid] = excl;
    int v = lo + tid;
    if (v < N) {
        rowptr[v] = pbase + excl;
        dinv[v] = rsqrtf((float)(cntl[tid] + 1));  // deg = indeg + 1 (self loop)
    }
    __syncthreads();
    for (int i = tid; i < cnt; i += 256) {
        int2 p = pairs[pbase + i];
        int pos = atomicAdd(&cur[p.y - lo], 1);
        csr[pbase + pos] = p.x;                          // 25 KB region, single block
    }
}

// ---------- GEMM + dinv prescale: G = dinv ⊙ (X @ W) ----------
// LDS-tiled, register-blocked: 64x64 output tile per block, 4x4 per thread,
// K chunked at 64. X tile padded (stride 68) -> <=2-way bank aliasing (free).
template <int K>
__global__ __launch_bounds__(256) void gemm_scale_kernel(
        const float* __restrict__ X, const float* __restrict__ W,
        const float* __restrict__ dinv, float* __restrict__ G, int N) {
    constexpr int KC  = 64;
    constexpr int XLD = KC + 4;           // padded row stride (floats)
    __shared__ float Xs[64 * XLD];        // 17408 B
    __shared__ float Wls[KC * CH];        // 16384 B
    int tid = threadIdx.x;
    int tx  = tid & 15;                   // output col group (4 cols)
    int ty  = tid >> 4;                   // output row group (4 rows)
    int row_tile = blockIdx.x * 64;
    int r0 = ty * 4;
    float acc[4][4] = {{0.f}};

    for (int kc = 0; kc < K; kc += KC) {
        __syncthreads();  // previous chunk's reads done before restage
#pragma unroll
        for (int t = 0; t < 4; ++t) {
            int idx = tid + t * 256;      // 0..1023
            int row = idx >> 4;
            int k4  = idx & 15;
            int grow = row_tile + row;
            const float4* xs = (const float4*)(X + (size_t)min(grow, N - 1) * K + kc);
            *(float4*)&Xs[row * XLD + 4 * k4] = xs[k4];
        }
#pragma unroll
        for (int t = 0; t < 4; ++t) {
            int idx = tid + t * 256;
            *(float4*)&Wls[idx * 4] = ((const float4*)(W + (size_t)kc * CH))[idx];
        }
        __syncthreads();
#pragma unroll
        for (int kk = 0; kk < KC; kk += 4) {
            float xr[4][4], wr[4][4];
#pragma unroll
            for (int i = 0; i < 4; ++i) {
                float4 v = *(const float4*)&Xs[(r0 + i) * XLD + kk];
                xr[i][0] = v.x; xr[i][1] = v.y; xr[i][2] = v.z; xr[i][3] = v.w;
            }
#pragma unroll
            for (int j = 0; j < 4; ++j) {
                float4 v = *(const float4*)&Wls[(kk + j) * CH + 4 * tx];
                wr[j][0] = v.x; wr[j][1] = v.y; wr[j][2] = v.z; wr[j][3] = v.w;
            }
#pragma unroll
            for (int i = 0; i < 4; ++i)
#pragma unroll
                for (int j = 0; j < 4; ++j)
#pragma unroll
                    for (int c = 0; c < 4; ++c)
                        acc[i][c] = fmaf(xr[i][j], wr[j][c], acc[i][c]);
        }
    }
#pragma unroll
    for (int i = 0; i < 4; ++i) {
        int r = row_tile + r0 + i;
        if (r < N) {
            float d = dinv[r];
            float4 o;
            o.x = acc[i][0] * d; o.y = acc[i][1] * d;
            o.z = acc[i][2] * d; o.w = acc[i][3] * d;
            ((float4*)G)[(size_t)r * 16 + tx] = o;
        }
    }
}

// ---------- gather aggregation: out[v] = dinv[v]*(g[v] + sum_{u -> v} g[u]) ----------
__global__ __launch_bounds__(256) void aggregate_kernel(
        const float* __restrict__ G, const int* __restrict__ rowptr,
        const int* __restrict__ csr, const float* __restrict__ dinv,
        float* __restrict__ Out, int N, int relu) {
    int lane = threadIdx.x & 63;
    int v = (blockIdx.x * 256 + threadIdx.x) >> 6;  // one wave per node
    if (v >= N) return;
    int grp = lane >> 4;   // 0..3 -> which edge in the 4-pack
    int cl  = lane & 15;   // float4 channel block
    const float4* __restrict__ G4 = (const float4*)G;

    int beg = rowptr[v], end = rowptr[v + 1];
    float4 acc = {0.f, 0.f, 0.f, 0.f};
#pragma unroll 4
    for (int e = beg; e < end; e += 4) {
        int eg = e + grp;
        int raw = csr[eg];            // csr padded: always in-bounds
        bool ok = eg < end;
        int u = ok ? raw : 0;
        float s = ok ? 1.f : 0.f;
        float4 g4 = G4[(size_t)u * 16 + cl];
        acc.x = fmaf(g4.x, s, acc.x);
        acc.y = fmaf(g4.y, s, acc.y);
        acc.z = fmaf(g4.z, s, acc.z);
        acc.w = fmaf(g4.w, s, acc.w);
    }
    acc.x += __shfl_xor(acc.x, 16); acc.y += __shfl_xor(acc.y, 16);
    acc.z += __shfl_xor(acc.z, 16); acc.w += __shfl_xor(acc.w, 16);
    acc.x += __shfl_xor(acc.x, 32); acc.y += __shfl_xor(acc.y, 32);
    acc.z += __shfl_xor(acc.z, 32); acc.w += __shfl_xor(acc.w, 32);

    if (lane < 16) {
        float4 self = G4[(size_t)v * 16 + lane];
        float d = dinv[v];
        float4 o;
        o.x = (acc.x + self.x) * d;
        o.y = (acc.y + self.y) * d;
        o.z = (acc.z + self.z) * d;
        o.w = (acc.w + self.w) * d;
        if (relu) {
            o.x = fmaxf(o.x, 0.f); o.y = fmaxf(o.y, 0.f);
            o.z = fmaxf(o.z, 0.f); o.w = fmaxf(o.w, 0.f);
        }
        ((float4*)Out)[(size_t)v * 16 + lane] = o;
    }
}

// ---------- graph boundaries via binary search (batch is sorted) ----------
__global__ void gptr_kernel(const int* __restrict__ batch, int* __restrict__ gptr,
                            int N, int NG) {
    int g = blockIdx.x * blockDim.x + threadIdx.x;
    if (g > NG) return;
    if (g == NG) { gptr[NG] = N; return; }
    int lo = 0, hi = N;
    while (lo < hi) {
        int mid = (lo + hi) >> 1;
        if (batch[mid] < g) lo = mid + 1; else hi = mid;
    }
    gptr[g] = lo;  // first index with batch[i] >= g
}

// ---------- fused mean-pool + linear head ----------
__global__ __launch_bounds__(64) void pool_head_kernel(
        const float* __restrict__ H, const int* __restrict__ gptr,
        const float* __restrict__ Wl, const float* __restrict__ bl,
        float* __restrict__ out, int NG) {
    int g = blockIdx.x;
    int lane = threadIdx.x;  // 64 = CH
    int s = gptr[g], e = gptr[g + 1];
    float acc = 0.f;
    for (int v = s; v < e; ++v) acc += H[(size_t)v * CH + lane];
    float c = (float)(e - s);
    float mean = (c > 0.f) ? acc / c : 0.f;
    for (int o = 0; o < 10; ++o) {
        float t = mean * Wl[lane * 10 + o];
        for (int off = 32; off > 0; off >>= 1) t += __shfl_down(t, off);
        if (lane == 0) out[g * 10 + o] = t + bl[o];
    }
}

extern "C" void kernel_launch(void* const* d_in, const int* in_sizes, int n_in,
                              void* d_out, int out_size, void* d_ws, size_t ws_size,
                              hipStream_t stream) {
    const float* x     = (const float*)d_in[0];
    const int*   ei    = (const int*)d_in[1];
    const int*   batch = (const int*)d_in[2];
    const float* W1    = (const float*)d_in[3];
    const float* W2    = (const float*)d_in[4];
    const float* W3    = (const float*)d_in[5];
    const float* Wl    = (const float*)d_in[6];
    const float* bl    = (const float*)d_in[7];
    float* out = (float*)d_out;

    const int N  = in_sizes[0] / 128;  // 50000
    const int E  = in_sizes[1] / 2;    // 1250000
    const int NG = out_size / 10;      // 500

    const int* src = ei;
    const int* dst = ei + E;

    // workspace carve-out (256B aligned)
    char* ws = (char*)d_ws;
    size_t off = 0;
    auto alloc = [&](size_t bytes) -> void* {
        void* p = ws + off;
        off += bytes;
        off = (off + 255) & ~(size_t)255;
        return p;
    };
    int*   bucket_cnt    = (int*)alloc((size_t)NBUCK * 4);
    int*   bucket_base   = (int*)alloc((size_t)(NBUCK + 1) * 4);
    int*   bucket_cursor = (int*)alloc((size_t)NBUCK * 4);
    int*   csr    = (int*)alloc((size_t)(E + 16) * 4);   // +pad: aggregate reads end+3
    int*   rowptr = (int*)alloc((size_t)(N + 1) * 4);
    float* dinv   = (float*)alloc((size_t)N * 4);
    int*   gptr   = (int*)alloc((size_t)(NG + 1) * 4);
    float* bufA   = (float*)alloc((size_t)N * CH * 4);   // also aliases pairs (10MB < 12.8MB)
    float* bufB   = (float*)alloc((size_t)N * CH * 4);
    int2*  pairs  = (int2*)bufA;  // CSR build finishes before gemm1 writes bufA

    hipMemsetAsync(bucket_cnt, 0, (size_t)NBUCK * 4, stream);

    int cb = (E + CHUNK - 1) / CHUNK;  // 306
    int wb = (N + 3) / 4;              // aggregate: 4 waves per block, 1 wave per node
    int gb = (N + 63) / 64;            // gemm: 64-row tiles

    bucket_hist_kernel<<<cb, 256, 0, stream>>>(dst, bucket_cnt, E);
    bucket_scan_kernel<<<1, 256, 0, stream>>>(bucket_cnt, bucket_base, bucket_cursor,
                                              rowptr, N, E);
    bin_kernel<<<cb, 256, 0, stream>>>(src, dst, bucket_cursor, pairs, E);
    bucket_sort_kernel<<<NBUCK, 256, 0, stream>>>(pairs, bucket_base, csr, rowptr, dinv, N);
    gptr_kernel<<<(NG + 512) / 512, 512, 0, stream>>>(batch, gptr, N, NG);

    // layer 1: 128 -> 64, relu   (gemm1 overwrites bufA/pairs -- CSR already built)
    gemm_scale_kernel<128><<<gb, 256, 0, stream>>>(x, W1, dinv, bufA, N);
    aggregate_kernel<<<wb, 256, 0, stream>>>(bufA, rowptr, csr, dinv, bufB, N, 1);
    // layer 2: 64 -> 64, relu
    gemm_scale_kernel<64><<<gb, 256, 0, stream>>>(bufB, W2, dinv, bufA, N);
    aggregate_kernel<<<wb, 256, 0, stream>>>(bufA, rowptr, csr, dinv, bufB, N, 1);
    // layer 3: 64 -> 64, no relu
    gemm_scale_kernel<64><<<gb, 256, 0, stream>>>(bufB, W3, dinv, bufA, N);
    aggregate_kernel<<<wb, 256, 0, stream>>>(bufA, rowptr, csr, dinv, bufB, N, 0);

    // mean pool + linear head
    pool_head_kernel<<<NG, 64, 0, stream>>>(bufB, gptr, Wl, bl, out, NG);
}

// Round 6
// 247.388 us; speedup vs baseline: 2.9273x; 1.1567x over previous
//
#include <hip/hip_runtime.h>

#define CH 64
#define CHUNK 4096
#define BSHIFT 8          // 256 nodes per bucket
#define NBUCK 196         // ceil(50000 / 256)

__device__ __forceinline__ unsigned short f2bf_rne(float f) {
    unsigned int u = __float_as_uint(f);
    u += 0x7fffu + ((u >> 16) & 1u);   // round to nearest even
    return (unsigned short)(u >> 16);
}
__device__ __forceinline__ float bf_lo(unsigned int q) {  // low bf16 of packed pair
    return __uint_as_float(q << 16);
}
__device__ __forceinline__ float bf_hi(unsigned int q) {  // high bf16
    return __uint_as_float(q & 0xffff0000u);
}

// ---------- pass 1: per-bucket histogram (dst >> 8) ----------
__global__ __launch_bounds__(256) void bucket_hist_kernel(
        const int* __restrict__ dst, int* __restrict__ bucket_cnt, int E) {
    __shared__ int hist[256];
    int tid = threadIdx.x;
    int e0 = blockIdx.x * CHUNK;
    int total = min(CHUNK, E - e0);
    hist[tid] = 0;
    __syncthreads();
    for (int i = tid; i < total; i += 256)
        atomicAdd(&hist[dst[e0 + i] >> BSHIFT], 1);
    __syncthreads();
    if (tid < NBUCK && hist[tid]) atomicAdd(&bucket_cnt[tid], hist[tid]);
}

// ---------- pass 2: scan bucket counts -> base & cursor ----------
__global__ __launch_bounds__(256) void bucket_scan_kernel(
        const int* __restrict__ cnt, int* __restrict__ base,
        int* __restrict__ cursor, int* __restrict__ rowptr, int N, int E) {
    __shared__ int sc[256];
    int tid = threadIdx.x;
    int c = (tid < NBUCK) ? cnt[tid] : 0;
    sc[tid] = c;
    __syncthreads();
    for (int off = 1; off < 256; off <<= 1) {
        int v = (tid >= off) ? sc[tid - off] : 0;
        __syncthreads();
        sc[tid] += v;
        __syncthreads();
    }
    if (tid < NBUCK) { base[tid] = sc[tid] - c; cursor[tid] = sc[tid] - c; }
    if (tid == NBUCK - 1) base[NBUCK] = sc[tid];
    if (tid == 0) rowptr[N] = E;
}

// ---------- pass 3: bin edges into bucket regions (coalesced flush) ----------
__global__ __launch_bounds__(256) void bin_kernel(
        const int* __restrict__ src, const int* __restrict__ dst,
        int* __restrict__ cursor, int2* __restrict__ pairs, int E) {
    __shared__ int2 stage[CHUNK];                         // 32 KB
    __shared__ int hist[256], sc[256], lbase[256], lcur[256], gbase[256];
    int tid = threadIdx.x;
    int e0 = blockIdx.x * CHUNK;
    int total = min(CHUNK, E - e0);
    hist[tid] = 0;
    __syncthreads();
    for (int i = tid; i < total; i += 256)
        atomicAdd(&hist[dst[e0 + i] >> BSHIFT], 1);
    __syncthreads();
    sc[tid] = hist[tid];
    __syncthreads();
    for (int off = 1; off < 256; off <<= 1) {
        int v = (tid >= off) ? sc[tid - off] : 0;
        __syncthreads();
        sc[tid] += v;
        __syncthreads();
    }
    lbase[tid] = sc[tid] - hist[tid];
    lcur[tid]  = sc[tid] - hist[tid];
    if (tid < NBUCK && hist[tid] > 0) gbase[tid] = atomicAdd(&cursor[tid], hist[tid]);
    __syncthreads();
    for (int i = tid; i < total; i += 256) {
        int s = src[e0 + i], d = dst[e0 + i];
        int pos = atomicAdd(&lcur[d >> BSHIFT], 1);
        stage[pos] = make_int2(s, d);
    }
    __syncthreads();
    for (int i = tid; i < total; i += 256) {
        int2 p = stage[i];
        int b = p.y >> BSHIFT;
        pairs[gbase[b] + (i - lbase[b])] = p;            // coalesced per segment
    }
}

// ---------- pass 4: per-bucket counting sort -> csr, rowptr, dinv ----------
__global__ __launch_bounds__(256) void bucket_sort_kernel(
        const int2* __restrict__ pairs, const int* __restrict__ base,
        int* __restrict__ csr, int* __restrict__ rowptr,
        float* __restrict__ dinv, int N) {
    __shared__ int cntl[256], sc[256], cur[256];
    int tid = threadIdx.x;
    int b = blockIdx.x;
    int lo = b << BSHIFT;
    int pbase = base[b], pend = base[b + 1];
    int cnt = pend - pbase;
    cntl[tid] = 0;
    __syncthreads();
    for (int i = tid; i < cnt; i += 256)
        atomicAdd(&cntl[pairs[pbase + i].y - lo], 1);
    __syncthreads();
    sc[tid] = cntl[tid];
    __syncthreads();
    for (int off = 1; off < 256; off <<= 1) {
        int v = (tid >= off) ? sc[tid - off] : 0;
        __syncthreads();
        sc[tid] += v;
        __syncthreads();
    }
    int excl = sc[tid] - cntl[tid];
    cur[tid] = excl;
    int v = lo + tid;
    if (v < N) {
        rowptr[v] = pbase + excl;
        dinv[v] = rsqrtf((float)(cntl[tid] + 1));  // deg = indeg + 1 (self loop)
    }
    __syncthreads();
    for (int i = tid; i < cnt; i += 256) {
        int2 p = pairs[pbase + i];
        int pos = atomicAdd(&cur[p.y - lo], 1);
        csr[pbase + pos] = p.x;                          // 25 KB region, single block
    }
}

// ---------- GEMM + dinv prescale: G = bf16( dinv ⊙ (X @ W) ) ----------
// LDS-tiled, register-blocked: 64x64 output tile per block, 4x4 per thread.
template <int K>
__global__ __launch_bounds__(256) void gemm_scale_kernel(
        const float* __restrict__ X, const float* __restrict__ W,
        const float* __restrict__ dinv, unsigned short* __restrict__ G, int N) {
    constexpr int KC  = 64;
    constexpr int XLD = KC + 4;           // padded row stride (floats)
    __shared__ float Xs[64 * XLD];        // 17408 B
    __shared__ float Wls[KC * CH];        // 16384 B
    int tid = threadIdx.x;
    int tx  = tid & 15;                   // output col group (4 cols)
    int ty  = tid >> 4;                   // output row group (4 rows)
    int row_tile = blockIdx.x * 64;
    int r0 = ty * 4;
    float acc[4][4] = {{0.f}};

    for (int kc = 0; kc < K; kc += KC) {
        __syncthreads();  // previous chunk's reads done before restage
#pragma unroll
        for (int t = 0; t < 4; ++t) {
            int idx = tid + t * 256;      // 0..1023
            int row = idx >> 4;
            int k4  = idx & 15;
            int grow = row_tile + row;
            const float4* xs = (const float4*)(X + (size_t)min(grow, N - 1) * K + kc);
            *(float4*)&Xs[row * XLD + 4 * k4] = xs[k4];
        }
#pragma unroll
        for (int t = 0; t < 4; ++t) {
            int idx = tid + t * 256;
            *(float4*)&Wls[idx * 4] = ((const float4*)(W + (size_t)kc * CH))[idx];
        }
        __syncthreads();
#pragma unroll
        for (int kk = 0; kk < KC; kk += 4) {
            float xr[4][4], wr[4][4];
#pragma unroll
            for (int i = 0; i < 4; ++i) {
                float4 v = *(const float4*)&Xs[(r0 + i) * XLD + kk];
                xr[i][0] = v.x; xr[i][1] = v.y; xr[i][2] = v.z; xr[i][3] = v.w;
            }
#pragma unroll
            for (int j = 0; j < 4; ++j) {
                float4 v = *(const float4*)&Wls[(kk + j) * CH + 4 * tx];
                wr[j][0] = v.x; wr[j][1] = v.y; wr[j][2] = v.z; wr[j][3] = v.w;
            }
#pragma unroll
            for (int i = 0; i < 4; ++i)
#pragma unroll
                for (int j = 0; j < 4; ++j)
#pragma unroll
                    for (int c = 0; c < 4; ++c)
                        acc[i][c] = fmaf(xr[i][j], wr[j][c], acc[i][c]);
        }
    }
#pragma unroll
    for (int i = 0; i < 4; ++i) {
        int r = row_tile + r0 + i;
        if (r < N) {
            float d = dinv[r];
            ushort4 o;
            o.x = f2bf_rne(acc[i][0] * d);
            o.y = f2bf_rne(acc[i][1] * d);
            o.z = f2bf_rne(acc[i][2] * d);
            o.w = f2bf_rne(acc[i][3] * d);
            ((ushort4*)G)[(size_t)r * 16 + tx] = o;
        }
    }
}

// ---------- gather aggregation: out[v] = dinv[v]*(g[v] + sum_{u -> v} g[u]) ----------
// One wave per node. 8 groups of 8 lanes; group g handles edge e+g; each lane
// reads uint4 = 8 bf16 channels -> one 1KB gather instruction covers 8 edges.
__global__ __launch_bounds__(256) void aggregate_kernel(
        const unsigned short* __restrict__ G, const int* __restrict__ rowptr,
        const int* __restrict__ csr, const float* __restrict__ dinv,
        float* __restrict__ Out, int N, int relu) {
    int lane = threadIdx.x & 63;
    int v = (blockIdx.x * 256 + threadIdx.x) >> 6;  // one wave per node
    if (v >= N) return;
    int grp = lane >> 3;   // 0..7 -> which edge in the 8-pack
    int cl  = lane & 7;    // 8-channel block (16 B of bf16)
    const uint4* __restrict__ G4 = (const uint4*)G;  // 8 uint4 per row

    int beg = rowptr[v], end = rowptr[v + 1];
    float a0 = 0.f, a1 = 0.f, a2 = 0.f, a3 = 0.f;
    float a4 = 0.f, a5 = 0.f, a6 = 0.f, a7 = 0.f;
#pragma unroll 2
    for (int e = beg; e < end; e += 8) {
        int eg = e + grp;
        int raw = csr[eg];            // csr padded: always in-bounds
        bool ok = eg < end;
        int u = ok ? raw : 0;
        float s = ok ? 1.f : 0.f;
        uint4 q = G4[(size_t)u * 8 + cl];
        a0 = fmaf(bf_lo(q.x), s, a0); a1 = fmaf(bf_hi(q.x), s, a1);
        a2 = fmaf(bf_lo(q.y), s, a2); a3 = fmaf(bf_hi(q.y), s, a3);
        a4 = fmaf(bf_lo(q.z), s, a4); a5 = fmaf(bf_hi(q.z), s, a5);
        a6 = fmaf(bf_lo(q.w), s, a6); a7 = fmaf(bf_hi(q.w), s, a7);
    }
    // reduce across the 8 groups (same channels in every group)
#pragma unroll
    for (int off = 8; off <= 32; off <<= 1) {
        a0 += __shfl_xor(a0, off); a1 += __shfl_xor(a1, off);
        a2 += __shfl_xor(a2, off); a3 += __shfl_xor(a3, off);
        a4 += __shfl_xor(a4, off); a5 += __shfl_xor(a5, off);
        a6 += __shfl_xor(a6, off); a7 += __shfl_xor(a7, off);
    }

    if (lane < 8) {
        uint4 q = G4[(size_t)v * 8 + lane];   // self loop term
        float d = dinv[v];
        float o0 = (a0 + bf_lo(q.x)) * d, o1 = (a1 + bf_hi(q.x)) * d;
        float o2 = (a2 + bf_lo(q.y)) * d, o3 = (a3 + bf_hi(q.y)) * d;
        float o4 = (a4 + bf_lo(q.z)) * d, o5 = (a5 + bf_hi(q.z)) * d;
        float o6 = (a6 + bf_lo(q.w)) * d, o7 = (a7 + bf_hi(q.w)) * d;
        if (relu) {
            o0 = fmaxf(o0, 0.f); o1 = fmaxf(o1, 0.f); o2 = fmaxf(o2, 0.f);
            o3 = fmaxf(o3, 0.f); o4 = fmaxf(o4, 0.f); o5 = fmaxf(o5, 0.f);
            o6 = fmaxf(o6, 0.f); o7 = fmaxf(o7, 0.f);
        }
        float4 w0 = {o0, o1, o2, o3}, w1 = {o4, o5, o6, o7};
        ((float4*)Out)[(size_t)v * 16 + lane * 2]     = w0;
        ((float4*)Out)[(size_t)v * 16 + lane * 2 + 1] = w1;
    }
}

// ---------- graph boundaries via binary search (batch is sorted) ----------
__global__ void gptr_kernel(const int* __restrict__ batch, int* __restrict__ gptr,
                            int N, int NG) {
    int g = blockIdx.x * blockDim.x + threadIdx.x;
    if (g > NG) return;
    if (g == NG) { gptr[NG] = N; return; }
    int lo = 0, hi = N;
    while (lo < hi) {
        int mid = (lo + hi) >> 1;
        if (batch[mid] < g) lo = mid + 1; else hi = mid;
    }
    gptr[g] = lo;  // first index with batch[i] >= g
}

// ---------- fused mean-pool + linear head ----------
__global__ __launch_bounds__(64) void pool_head_kernel(
        const float* __restrict__ H, const int* __restrict__ gptr,
        const float* __restrict__ Wl, const float* __restrict__ bl,
        float* __restrict__ out, int NG) {
    int g = blockIdx.x;
    int lane = threadIdx.x;  // 64 = CH
    int s = gptr[g], e = gptr[g + 1];
    float acc = 0.f;
    for (int v = s; v < e; ++v) acc += H[(size_t)v * CH + lane];
    float c = (float)(e - s);
    float mean = (c > 0.f) ? acc / c : 0.f;
    for (int o = 0; o < 10; ++o) {
        float t = mean * Wl[lane * 10 + o];
        for (int off = 32; off > 0; off >>= 1) t += __shfl_down(t, off);
        if (lane == 0) out[g * 10 + o] = t + bl[o];
    }
}

extern "C" void kernel_launch(void* const* d_in, const int* in_sizes, int n_in,
                              void* d_out, int out_size, void* d_ws, size_t ws_size,
                              hipStream_t stream) {
    const float* x     = (const float*)d_in[0];
    const int*   ei    = (const int*)d_in[1];
    const int*   batch = (const int*)d_in[2];
    const float* W1    = (const float*)d_in[3];
    const float* W2    = (const float*)d_in[4];
    const float* W3    = (const float*)d_in[5];
    const float* Wl    = (const float*)d_in[6];
    const float* bl    = (const float*)d_in[7];
    float* out = (float*)d_out;

    const int N  = in_sizes[0] / 128;  // 50000
    const int E  = in_sizes[1] / 2;    // 1250000
    const int NG = out_size / 10;      // 500

    const int* src = ei;
    const int* dst = ei + E;

    // workspace carve-out (256B aligned)
    char* ws = (char*)d_ws;
    size_t off = 0;
    auto alloc = [&](size_t bytes) -> void* {
        void* p = ws + off;
        off += bytes;
        off = (off + 255) & ~(size_t)255;
        return p;
    };
    int*   bucket_cnt    = (int*)alloc((size_t)NBUCK * 4);
    int*   bucket_base   = (int*)alloc((size_t)(NBUCK + 1) * 4);
    int*   bucket_cursor = (int*)alloc((size_t)NBUCK * 4);
    int*   csr    = (int*)alloc((size_t)(E + 16) * 4);   // +pad: aggregate reads end+7
    int*   rowptr = (int*)alloc((size_t)(N + 1) * 4);
    float* dinv   = (float*)alloc((size_t)N * 4);
    int*   gptr   = (int*)alloc((size_t)(NG + 1) * 4);
    unsigned short* Gbf = (unsigned short*)alloc((size_t)N * CH * 2);  // bf16 messages, 6.4MB
    float* hbuf   = (float*)alloc((size_t)N * CH * 4);   // f32 hidden, 12.8MB; aliases pairs
    int2*  pairs  = (int2*)hbuf;  // CSR build finishes before aggregate writes hbuf

    hipMemsetAsync(bucket_cnt, 0, (size_t)NBUCK * 4, stream);

    int cb = (E + CHUNK - 1) / CHUNK;  // 306
    int wb = (N + 3) / 4;              // aggregate: 4 waves per block, 1 wave per node
    int gb = (N + 63) / 64;            // gemm: 64-row tiles

    bucket_hist_kernel<<<cb, 256, 0, stream>>>(dst, bucket_cnt, E);
    bucket_scan_kernel<<<1, 256, 0, stream>>>(bucket_cnt, bucket_base, bucket_cursor,
                                              rowptr, N, E);
    bin_kernel<<<cb, 256, 0, stream>>>(src, dst, bucket_cursor, pairs, E);
    bucket_sort_kernel<<<NBUCK, 256, 0, stream>>>(pairs, bucket_base, csr, rowptr, dinv, N);
    gptr_kernel<<<(NG + 512) / 512, 512, 0, stream>>>(batch, gptr, N, NG);

    // layer 1: 128 -> 64, relu
    gemm_scale_kernel<128><<<gb, 256, 0, stream>>>(x, W1, dinv, Gbf, N);
    aggregate_kernel<<<wb, 256, 0, stream>>>(Gbf, rowptr, csr, dinv, hbuf, N, 1);
    // layer 2: 64 -> 64, relu
    gemm_scale_kernel<64><<<gb, 256, 0, stream>>>(hbuf, W2, dinv, Gbf, N);
    aggregate_kernel<<<wb, 256, 0, stream>>>(Gbf, rowptr, csr, dinv, hbuf, N, 1);
    // layer 3: 64 -> 64, no relu
    gemm_scale_kernel<64><<<gb, 256, 0, stream>>>(hbuf, W3, dinv, Gbf, N);
    aggregate_kernel<<<wb, 256, 0, stream>>>(Gbf, rowptr, csr, dinv, hbuf, N, 0);

    // mean pool + linear head
    pool_head_kernel<<<NG, 64, 0, stream>>>(hbuf, gptr, Wl, bl, out, NG);
}